// Round 4
// baseline (16160.542 us; speedup 1.0000x reference)
//
#include <hip/hip_runtime.h>
#include <hip/hip_bf16.h>

#define N_  64
#define T_  512
#define D_  512
#define H_  512
#define FH  2048   // 4H
#define K1  1024   // hi|lo packed columns
#define NWG 256
#define NSTEPWG 128
#define BLK 256

typedef __attribute__((ext_vector_type(4))) float f32x4;
typedef __attribute__((ext_vector_type(8))) short bf16x8;

__device__ __forceinline__ unsigned short f2bf(float f) {
  unsigned u = __float_as_uint(f);
  return (unsigned short)((u + 0x7FFFu + ((u >> 16) & 1u)) >> 16);
}
__device__ __forceinline__ float bf2f(unsigned short s) {
  return __uint_as_float(((unsigned)s) << 16);
}

__device__ __forceinline__ void gl_lds16(const void* g, void* l) {
  __builtin_amdgcn_global_load_lds(
      (const __attribute__((address_space(1))) void*)g,
      (__attribute__((address_space(3))) void*)l, 16, 0, 0);
}

// Full-grid barrier: monotonic-generation atomic counter (agent scope).
// Spin-capped: a logic bug produces wrong data (detectable) instead of a hang.
template <int SLP>
__device__ __forceinline__ void gbar(unsigned* cnt, unsigned* rel, unsigned gen,
                                     unsigned nwg) {
  __syncthreads();
  if (threadIdx.x == 0) {
    unsigned old = __hip_atomic_fetch_add(cnt, 1u, __ATOMIC_ACQ_REL,
                                          __HIP_MEMORY_SCOPE_AGENT);
    if (old == gen * nwg - 1u) {
      __hip_atomic_store(rel, gen, __ATOMIC_RELEASE, __HIP_MEMORY_SCOPE_AGENT);
    } else {
      int guard = 0;
      while (__hip_atomic_load(rel, __ATOMIC_ACQUIRE,
                               __HIP_MEMORY_SCOPE_AGENT) < gen) {
        __builtin_amdgcn_s_sleep(SLP);
        if (++guard > (1 << 22)) break;
      }
    }
  }
  __syncthreads();
}

// Step barrier for the 128 step-WGs: slot-array arrival (no RMW serialization).
// WG w release-stores arr[w]=gen; WG0 wave0 polls all 128 slots (2 coalesced
// loads + __all), then release-stores rel=gen; others acquire-poll rel.
__device__ __forceinline__ void step_bar(unsigned* arr, unsigned* rel,
                                         unsigned gen, int wg) {
  __syncthreads();
  const int tid = threadIdx.x;
  if (tid == 0)
    __hip_atomic_store(&arr[wg], gen, __ATOMIC_RELEASE,
                       __HIP_MEMORY_SCOPE_AGENT);
  if (wg == 0) {
    if (tid < 64) {
      int guard = 0;
      for (;;) {
        unsigned a0 = __hip_atomic_load(&arr[tid], __ATOMIC_ACQUIRE,
                                        __HIP_MEMORY_SCOPE_AGENT);
        unsigned a1 = __hip_atomic_load(&arr[tid + 64], __ATOMIC_ACQUIRE,
                                        __HIP_MEMORY_SCOPE_AGENT);
        if (__all(a0 >= gen && a1 >= gen)) break;
        __builtin_amdgcn_s_sleep(0);
        if (++guard > (1 << 22)) break;
      }
      if (tid == 0)
        __hip_atomic_store(rel, gen, __ATOMIC_RELEASE,
                           __HIP_MEMORY_SCOPE_AGENT);
    }
  } else if (tid == 0) {
    int guard = 0;
    while (__hip_atomic_load(rel, __ATOMIC_ACQUIRE,
                             __HIP_MEMORY_SCOPE_AGENT) < gen) {
      __builtin_amdgcn_s_sleep(0);
      if (++guard > (1 << 22)) break;
    }
  }
  __syncthreads();
}

// K'=1536 3-pass split-bf16 GEMM mapping:
//   A' = [Ahi | Ahi | Alo], B' = [Bhi | Blo | Bhi], both stored as [hi(512)|lo(512)].
//   A src col = (kk<16 ? kk : kk-16)*32 ; B src row = (kk<32 ? kk : kk-32)*32.
// LWH=true: Wh slice persistent in 128 KiB STATIC LDS (XOR-swizzled).
// LWH=false: fallback — read Wh fragments from global each step.
template <bool LWH>
__global__ void __launch_bounds__(BLK, 1)
lstm_persistent(const float* __restrict__ x, const float* __restrict__ h0,
                const float* __restrict__ Wx, const float* __restrict__ Wh,
                const float* __restrict__ b, float* __restrict__ out,
                void* __restrict__ ws, int Tc) {
  __shared__ __align__(16) short wlds[LWH ? 64 * K1 : 8];  // 128 KiB Wh slice
  __shared__ __align__(16) short Asm[128 * 32];            // 8 KiB
  __shared__ __align__(16) short Bsm[128 * 32];            // 8 KiB
  __shared__ float glds[4][16][16];                        // 4 KiB

  char* wsb = (char*)ws;
  unsigned* cntF = (unsigned*)(wsb + 0);
  unsigned* relF = (unsigned*)(wsb + 64);
  unsigned* relH = (unsigned*)(wsb + 128);
  unsigned* arrH = (unsigned*)(wsb + 512);       // 128 slots
  short* Wxt   = (short*)(wsb + 1024);           // [2048][1024] bf16 (hi|lo), W^T
  short* Wht   = Wxt + (size_t)FH * K1;          // [2048][1024]
  short* hbuf0 = Wht + (size_t)FH * K1;          // [64][1024] bf16 (hi|lo)
  short* hbuf1 = hbuf0 + N_ * K1;
  float* cbuf  = (float*)(hbuf1 + N_ * K1);      // [64][512] f32
  short* xprim = (short*)(cbuf + N_ * H_);       // [Tc*64][1024] bf16 (hi|lo)
  float* xwxb  = (float*)(xprim + (size_t)Tc * N_ * K1); // [Tc*64][2048] f32

  const int tid = threadIdx.x;
  const int wg = blockIdx.x;
  const int gtid = wg * BLK + tid;
  const int lane = tid & 63;
  const int wv = tid >> 6;

  unsigned genF = 0, genH = 0;

  // ---- prep: split-transpose weights into [j][k_hi | k_lo] bf16 ----
  for (int idx = gtid; idx < 2 * D_ * FH; idx += NWG * BLK) {
    int m = idx >> 20;                 // 0 = Wx, 1 = Wh   (D_*FH = 1<<20)
    int rr = idx & ((1 << 20) - 1);
    int j = rr >> 9;
    int k = rr & 511;
    float v = (m ? Wh : Wx)[(size_t)k * FH + j];
    unsigned short hi = f2bf(v);
    unsigned short lo = f2bf(v - bf2f(hi));
    short* dst = m ? Wht : Wxt;
    dst[(size_t)j * K1 + k] = (short)hi;
    dst[(size_t)j * K1 + 512 + k] = (short)lo;
  }
  // ---- h0 -> hi/lo bf16, c = 0 ----
  for (int idx = gtid; idx < N_ * H_; idx += NWG * BLK) {
    int n = idx >> 9, k = idx & 511;
    float v = h0[idx];
    unsigned short hi = f2bf(v);
    unsigned short lo = f2bf(v - bf2f(hi));
    hbuf0[n * K1 + k] = (short)hi;
    hbuf0[n * K1 + 512 + k] = (short)lo;
    cbuf[idx] = 0.0f;
  }
  gbar<4>(cntF, relF, ++genF, NWG);

  // ---- step WGs: load persistent Wh slice into LDS (XOR-swizzled 16B units) ----
  if constexpr (LWH) {
    if (wg < NSTEPWG) {
      const int cg = wg >> 2;
      for (int u = tid; u < 64 * 128; u += BLK) {
        int lc = u >> 7, k16 = u & 127;
        int gc = ((lc >> 4) << 9) + cg * 16 + (lc & 15); // gate*512 + cg*16 + col
        int4 v = *(const int4*)(Wht + (size_t)gc * K1 + k16 * 8);
        *(int4*)(wlds + lc * K1 + ((k16 ^ (lc & 7)) << 3)) = v;
      }
    }
    __syncthreads();
  }

  const int nCh = T_ / Tc;
  const int Mch = Tc * N_;
  const int wm = wv >> 1, wn = wv & 1;

  for (int ch = 0; ch < nCh; ++ch) {
    const int t0 = ch * Tc;

    // -------- x chunk -> hi/lo bf16, row m = tl*64 + n --------
    for (int idx = gtid; idx < Mch * D_; idx += NWG * BLK) {
      int mrow = idx >> 9, d = idx & 511;
      int tl = mrow >> 6, n = mrow & 63;
      float v = x[((size_t)n * T_ + (t0 + tl)) * D_ + d];
      unsigned short hi = f2bf(v);
      unsigned short lo = f2bf(v - bf2f(hi));
      xprim[(size_t)mrow * K1 + d] = (short)hi;
      xprim[(size_t)mrow * K1 + 512 + d] = (short)lo;
    }
    gbar<2>(cntF, relF, ++genF, NWG);

    // -------- phase 1: xwxb = x' @ Wx' + b  (128x128 tiles, K'=1536) --------
    // LDS staging XOR-swizzle (both-sides, rule 21): source slot ^= (row>>1)&3,
    // gl_lds dest stays linear, fragment read un-XORs -> 2-way conflicts (free).
    const int nTiles = (Mch >> 7) * (FH >> 7);
    const int sslot = (lane & 3) ^ ((lane >> 3) & 3);  // (lane&3) ^ ((row>>1)&3)
    for (int tile = wg; tile < nTiles; tile += NWG) {
      int tm = tile >> 4, tn = tile & 15;
      int m0 = tm << 7, n0 = tn << 7;
      f32x4 acc[4][4];
      for (int i = 0; i < 4; ++i)
        for (int j = 0; j < 4; ++j) acc[i][j] = (f32x4){0.f, 0.f, 0.f, 0.f};
      for (int kk = 0; kk < 48; ++kk) {
        int ac = (kk < 16 ? kk : kk - 16) << 5;
        int bc = (kk < 32 ? kk : kk - 32) << 5;
        __syncthreads();
        {
          const short* sa =
              xprim + (size_t)(m0 + wv * 32 + (lane >> 2)) * K1 + ac + sslot * 8;
          gl_lds16(sa, Asm + (wv * 32) * 32);
          gl_lds16(sa + (size_t)16 * K1, Asm + (wv * 32 + 16) * 32);
          const short* sb =
              Wxt + (size_t)(n0 + wv * 32 + (lane >> 2)) * K1 + bc + sslot * 8;
          gl_lds16(sb, Bsm + (wv * 32) * 32);
          gl_lds16(sb + (size_t)16 * K1, Bsm + (wv * 32 + 16) * 32);
        }
        __syncthreads();
        bf16x8 af[4], bfr[4];
        for (int mi = 0; mi < 4; ++mi) {
          int R = wm * 64 + mi * 16 + (lane & 15);
          int rs = ((lane >> 4) & 3) ^ ((R >> 1) & 3);
          af[mi] = *(const bf16x8*)(Asm + R * 32 + rs * 8);
        }
        for (int ni = 0; ni < 4; ++ni) {
          int R = wn * 64 + ni * 16 + (lane & 15);
          int rs = ((lane >> 4) & 3) ^ ((R >> 1) & 3);
          bfr[ni] = *(const bf16x8*)(Bsm + R * 32 + rs * 8);
        }
        for (int mi = 0; mi < 4; ++mi)
          for (int ni = 0; ni < 4; ++ni)
            acc[mi][ni] = __builtin_amdgcn_mfma_f32_16x16x32_bf16(
                af[mi], bfr[ni], acc[mi][ni], 0, 0, 0);
      }
      for (int ni = 0; ni < 4; ++ni) {
        float bj = b[n0 + wn * 64 + ni * 16 + (lane & 15)];
        for (int mi = 0; mi < 4; ++mi) {
          int mg = m0 + wm * 64 + mi * 16 + ((lane >> 4) << 2);
          float* dst =
              xwxb + (size_t)mg * FH + n0 + wn * 64 + ni * 16 + (lane & 15);
          for (int r = 0; r < 4; ++r) dst[(size_t)r * FH] = acc[mi][ni][r] + bj;
        }
      }
    }
    gbar<2>(cntF, relF, ++genF, NWG);

    // -------- recurrent steps: 128 WGs, 1 slot-barrier/step --------
    if (wg < NSTEPWG) {
      const int rb = wg & 3, cg = wg >> 2;
      const int lc = wv * 16 + (lane & 15);
      const int gcl = wv * 512 + cg * 16 + (lane & 15);  // global Wh' row (fallback)
      for (int tl = 0; tl < Tc; ++tl) {
        int tg = t0 + tl;
        const short* hc = (tg & 1) ? hbuf1 : hbuf0;
        short* hn = (tg & 1) ? hbuf0 : hbuf1;
        f32x4 acc0 = {0.f, 0.f, 0.f, 0.f};
        f32x4 acc1 = {0.f, 0.f, 0.f, 0.f};
        const short* arow =
            hc + (size_t)(rb * 16 + (lane & 15)) * K1 + (lane >> 4) * 8;
#pragma unroll
        for (int kk = 0; kk < 48; ++kk) {
          int ab = (kk < 16 ? kk : kk - 16) << 5;
          int bb = (kk < 32 ? kk : kk - 32) << 5;
          bf16x8 av = *(const bf16x8*)(arow + ab);
          bf16x8 bv;
          if constexpr (LWH) {
            int k16 = (bb >> 3) + (lane >> 4);
            bv = *(const bf16x8*)(wlds + lc * K1 + ((k16 ^ (lc & 7)) << 3));
          } else {
            bv = *(const bf16x8*)(Wht + (size_t)gcl * K1 + bb + (lane >> 4) * 8);
          }
          if (kk & 1)
            acc1 = __builtin_amdgcn_mfma_f32_16x16x32_bf16(av, bv, acc1, 0, 0, 0);
          else
            acc0 = __builtin_amdgcn_mfma_f32_16x16x32_bf16(av, bv, acc0, 0, 0, 0);
        }
        f32x4 a = acc0 + acc1;
        for (int r = 0; r < 4; ++r)
          glds[wv][((lane >> 4) << 2) + r][lane & 15] = a[r];
        __syncthreads();
        {
          int row = tid >> 4, col = tid & 15;
          int n = rb * 16 + row, jh = cg * 16 + col;
          const float* xr = xwxb + ((size_t)tl * 64 + n) * FH + jh;
          float gi = glds[0][row][col] + xr[0];
          float gf = glds[1][row][col] + xr[512];
          float go = glds[2][row][col] + xr[1024];
          float gg = glds[3][row][col] + xr[1536];
          float si = 1.0f / (1.0f + __expf(-gi));
          float sf = 1.0f / (1.0f + __expf(-gf));
          float so = 1.0f / (1.0f + __expf(-go));
          float tg2 = tanhf(gg);
          float cn = sf * cbuf[n * H_ + jh] + si * tg2;
          cbuf[n * H_ + jh] = cn;
          float hv = so * tanhf(cn);
          out[((size_t)n * T_ + tg) * H_ + jh] = hv;
          unsigned short hi = f2bf(hv);
          unsigned short lo = f2bf(hv - bf2f(hi));
          hn[n * K1 + jh] = (short)hi;
          hn[n * K1 + 512 + jh] = (short)lo;
        }
        step_bar(arrH, relH, ++genH, wg);
      }
    } else {
      genH += Tc;
    }
    gbar<4>(cntF, relF, ++genF, NWG);
  }
}

extern "C" void kernel_launch(void* const* d_in, const int* in_sizes, int n_in,
                              void* d_out, int out_size, void* d_ws, size_t ws_size,
                              hipStream_t stream) {
  (void)in_sizes; (void)n_in; (void)out_size;
  const float* x  = (const float*)d_in[0];
  const float* h0 = (const float*)d_in[1];
  const float* Wx = (const float*)d_in[2];
  const float* Wh = (const float*)d_in[3];
  const float* b  = (const float*)d_in[4];
  float* out = (float*)d_out;

  // ws: 1KB barriers + 8MB weights + 2x128KB h + 128KB c + Tc*(128KB x' + 512KB xwxb)
  size_t fixed = 1024 + 2 * (size_t)FH * K1 * 2 + 2 * (size_t)N_ * K1 * 2 +
                 (size_t)N_ * H_ * 4;
  size_t perTc = (size_t)N_ * K1 * 2 + (size_t)N_ * FH * 4;
  int Tc = 64;
  while (Tc > 1 && fixed + (size_t)Tc * perTc > ws_size) Tc >>= 1;

  (void)hipMemsetAsync(d_ws, 0, 1024, stream);  // reset barriers every replay

  void* args[] = {(void*)&x, (void*)&h0, (void*)&Wx, (void*)&Wh,
                  (void*)&b, (void*)&out, (void*)&d_ws, (void*)&Tc};

  // Path A: cooperative launch (static 148 KiB LDS -> 1 WG/CU, 256 WGs fit).
  hipError_t e = hipLaunchCooperativeKernel((void*)lstm_persistent<true>,
                                            dim3(NWG), dim3(BLK), args, 0,
                                            stream);
  if (e != hipSuccess) {
    // Path B: plain launch (custom barrier only needs co-residency, which
    // 1 WG/CU x 256 CUs guarantees).
    (void)hipGetLastError();
    lstm_persistent<true><<<dim3(NWG), dim3(BLK), 0, stream>>>(
        x, h0, Wx, Wh, b, out, d_ws, Tc);
    e = hipGetLastError();
  }
  if (e != hipSuccess) {
    // Path C: fallback — Wh read from global, tiny LDS.
    (void)hipGetLastError();
    lstm_persistent<false><<<dim3(NWG), dim3(BLK), 0, stream>>>(
        x, h0, Wx, Wh, b, out, d_ws, Tc);
    (void)hipGetLastError();
  }
}

// Round 5
// 4279.403 us; speedup vs baseline: 3.7764x; 3.7764x over previous
//
#include <hip/hip_runtime.h>
#include <hip/hip_bf16.h>

#define N_  64
#define T_  512
#define D_  512
#define H_  512
#define FH  2048   // 4H
#define K1  1024   // hi|lo packed columns
#define NWG 256
#define NSTEPWG 128
#define BLK 256

typedef __attribute__((ext_vector_type(4))) float f32x4;
typedef __attribute__((ext_vector_type(8))) short bf16x8;

__device__ __forceinline__ unsigned short f2bf(float f) {
  unsigned u = __float_as_uint(f);
  return (unsigned short)((u + 0x7FFFu + ((u >> 16) & 1u)) >> 16);
}
__device__ __forceinline__ float bf2f(unsigned short s) {
  return __uint_as_float(((unsigned)s) << 16);
}

__device__ __forceinline__ void gl_lds16(const void* g, void* l) {
  __builtin_amdgcn_global_load_lds(
      (const __attribute__((address_space(1))) void*)g,
      (__attribute__((address_space(3))) void*)l, 16, 0, 0);
}

// LLC-coherent 16B load (bypasses L1+L2; pairs with sc0 sc1 write-through
// stores for cross-XCD h handoff without any cache-maintenance fences).
__device__ __forceinline__ bf16x8 ld16_cc(const short* p) {
  bf16x8 d;
  asm volatile("global_load_dwordx4 %0, %1, off sc0 sc1" : "=v"(d) : "v"(p));
  return d;
}
__device__ __forceinline__ void st4_cc(short* p, unsigned v) {
  asm volatile("global_store_dword %0, %1, off sc0 sc1" ::"v"(p), "v"(v)
               : "memory");
}

// Full-grid barrier: relaxed counter + ONE release/acquire fence pair per WG
// (no per-poll buffer_inv). Spin-capped: bug -> wrong data, not a hang.
template <int SLP>
__device__ __forceinline__ void gbar(unsigned* cnt, unsigned* rel, unsigned gen,
                                     unsigned nwg) {
  __syncthreads();  // drains all WG memory ops to L2
  if (threadIdx.x == 0) {
    __builtin_amdgcn_fence(__ATOMIC_RELEASE, "agent");  // wbl2 once
    unsigned old = __hip_atomic_fetch_add(cnt, 1u, __ATOMIC_RELAXED,
                                          __HIP_MEMORY_SCOPE_AGENT);
    if (old == gen * nwg - 1u) {
      __hip_atomic_store(rel, gen, __ATOMIC_RELAXED, __HIP_MEMORY_SCOPE_AGENT);
    } else {
      int guard = 0;
      while (__hip_atomic_load(rel, __ATOMIC_RELAXED,
                               __HIP_MEMORY_SCOPE_AGENT) < gen) {
        __builtin_amdgcn_s_sleep(SLP);
        if (++guard > (1 << 22)) break;
      }
    }
    __builtin_amdgcn_fence(__ATOMIC_ACQUIRE, "agent");  // inv once
  }
  __syncthreads();
}

// K'=1536 3-pass split-bf16 GEMM mapping:
//   A' = [Ahi | Ahi | Alo], B' = [Bhi | Blo | Bhi], both stored as [hi(512)|lo(512)].
template <bool LWH>
__global__ void __launch_bounds__(BLK, 1)
lstm_persistent(const float* __restrict__ x, const float* __restrict__ h0,
                const float* __restrict__ Wx, const float* __restrict__ Wh,
                const float* __restrict__ b, float* __restrict__ out,
                void* __restrict__ ws, int Tc) {
  __shared__ __align__(16) short wlds[LWH ? 64 * K1 : 8];  // 128 KiB Wh slice
  __shared__ __align__(16) short Asm[128 * 32];            // 8 KiB
  __shared__ __align__(16) short Bsm[128 * 32];            // 8 KiB
  __shared__ float glds[4][16][16];                        // 4 KiB

  char* wsb = (char*)ws;
  unsigned* cntF = (unsigned*)(wsb + 0);
  unsigned* relF = (unsigned*)(wsb + 64);
  unsigned* arrH = (unsigned*)(wsb + 512);       // 128 step flags (rb*32+cg)
  short* Wxt   = (short*)(wsb + 1024);           // [2048][1024] bf16 (hi|lo), W^T
  short* Wht   = Wxt + (size_t)FH * K1;          // [2048][1024]
  short* hbuf0 = Wht + (size_t)FH * K1;          // [64][1024] bf16 (hi|lo)
  short* hbuf1 = hbuf0 + N_ * K1;
  float* cbuf  = (float*)(hbuf1 + N_ * K1);      // [64][512] f32
  short* xprim = (short*)(cbuf + N_ * H_);       // [Tc*64][1024] bf16 (hi|lo)
  float* xwxb  = (float*)(xprim + (size_t)Tc * N_ * K1); // [Tc*64][2048] f32

  const int tid = threadIdx.x;
  const int wg = blockIdx.x;
  const int gtid = wg * BLK + tid;
  const int lane = tid & 63;
  const int wv = tid >> 6;

  unsigned genF = 0;
  unsigned fl = 0;  // steps completed (step-flag generation)

  // ---- prep: split-transpose weights, octet-wise (coalesced R and W) ----
  for (int idx = gtid; idx < 2 * FH * 64; idx += NWG * BLK) {
    int m = idx >> 17;                 // FH*64 = 131072
    int rr = idx & 131071;
    int j = rr >> 6;
    int oct = rr & 63;
    const float* W = m ? Wh : Wx;
    bf16x8 hv, lv;
#pragma unroll
    for (int i = 0; i < 8; ++i) {
      float v = W[(size_t)(oct * 8 + i) * FH + j];
      unsigned short h = f2bf(v);
      hv[i] = (short)h;
      lv[i] = (short)f2bf(v - bf2f(h));
    }
    short* dst = m ? Wht : Wxt;
    *(bf16x8*)(dst + (size_t)j * K1 + oct * 8) = hv;
    *(bf16x8*)(dst + (size_t)j * K1 + 512 + oct * 8) = lv;
  }
  // ---- h0 -> hi/lo bf16, c = 0 ----
  for (int idx = gtid; idx < N_ * H_; idx += NWG * BLK) {
    int n = idx >> 9, k = idx & 511;
    float v = h0[idx];
    unsigned short hi = f2bf(v);
    unsigned short lo = f2bf(v - bf2f(hi));
    hbuf0[n * K1 + k] = (short)hi;
    hbuf0[n * K1 + 512 + k] = (short)lo;
    cbuf[idx] = 0.0f;
  }
  gbar<4>(cntF, relF, ++genF, NWG);

  // ---- step WGs: load persistent Wh slice into LDS (XOR-swizzled 16B units) ----
  if constexpr (LWH) {
    if (wg < NSTEPWG) {
      const int cg = wg >> 2;
      for (int u = tid; u < 64 * 128; u += BLK) {
        int lc = u >> 7, k16 = u & 127;
        int gc = ((lc >> 4) << 9) + cg * 16 + (lc & 15); // gate*512 + cg*16 + col
        int4 v = *(const int4*)(Wht + (size_t)gc * K1 + k16 * 8);
        *(int4*)(wlds + lc * K1 + ((k16 ^ (lc & 7)) << 3)) = v;
      }
    }
    __syncthreads();
  }

  const int nCh = T_ / Tc;
  const int Mch = Tc * N_;
  const int wm = wv >> 1, wn = wv & 1;

  for (int ch = 0; ch < nCh; ++ch) {
    const int t0 = ch * Tc;

    // -------- x chunk -> hi/lo bf16 (octet-wise, vector stores) --------
    for (int idx = gtid; idx < Mch * 64; idx += NWG * BLK) {
      int mrow = idx >> 6, oct = idx & 63;
      int tl = mrow >> 6, n = mrow & 63;
      const float* src = x + ((size_t)n * T_ + (t0 + tl)) * D_ + oct * 8;
      bf16x8 hv, lv;
#pragma unroll
      for (int i = 0; i < 8; ++i) {
        float v = src[i];
        unsigned short h = f2bf(v);
        hv[i] = (short)h;
        lv[i] = (short)f2bf(v - bf2f(h));
      }
      *(bf16x8*)(xprim + (size_t)mrow * K1 + oct * 8) = hv;
      *(bf16x8*)(xprim + (size_t)mrow * K1 + 512 + oct * 8) = lv;
    }
    gbar<2>(cntF, relF, ++genF, NWG);

    // -------- phase 1: xwxb = x' @ Wx' + b  (128x128 tiles, K'=1536) --------
    const int nTiles = (Mch >> 7) * (FH >> 7);
    const int sslot = (lane & 3) ^ ((lane >> 3) & 3);
    for (int tile = wg; tile < nTiles; tile += NWG) {
      int tm = tile >> 4, tn = tile & 15;
      int m0 = tm << 7, n0 = tn << 7;
      f32x4 acc[4][4];
      for (int i = 0; i < 4; ++i)
        for (int j = 0; j < 4; ++j) acc[i][j] = (f32x4){0.f, 0.f, 0.f, 0.f};
      for (int kk = 0; kk < 48; ++kk) {
        int ac = (kk < 16 ? kk : kk - 16) << 5;
        int bc = (kk < 32 ? kk : kk - 32) << 5;
        __syncthreads();
        {
          const short* sa =
              xprim + (size_t)(m0 + wv * 32 + (lane >> 2)) * K1 + ac + sslot * 8;
          gl_lds16(sa, Asm + (wv * 32) * 32);
          gl_lds16(sa + (size_t)16 * K1, Asm + (wv * 32 + 16) * 32);
          const short* sb =
              Wxt + (size_t)(n0 + wv * 32 + (lane >> 2)) * K1 + bc + sslot * 8;
          gl_lds16(sb, Bsm + (wv * 32) * 32);
          gl_lds16(sb + (size_t)16 * K1, Bsm + (wv * 32 + 16) * 32);
        }
        __syncthreads();
        bf16x8 af[4], bfr[4];
        for (int mi = 0; mi < 4; ++mi) {
          int R = wm * 64 + mi * 16 + (lane & 15);
          int rs = ((lane >> 4) & 3) ^ ((R >> 1) & 3);
          af[mi] = *(const bf16x8*)(Asm + R * 32 + rs * 8);
        }
        for (int ni = 0; ni < 4; ++ni) {
          int R = wn * 64 + ni * 16 + (lane & 15);
          int rs = ((lane >> 4) & 3) ^ ((R >> 1) & 3);
          bfr[ni] = *(const bf16x8*)(Bsm + R * 32 + rs * 8);
        }
        for (int mi = 0; mi < 4; ++mi)
          for (int ni = 0; ni < 4; ++ni)
            acc[mi][ni] = __builtin_amdgcn_mfma_f32_16x16x32_bf16(
                af[mi], bfr[ni], acc[mi][ni], 0, 0, 0);
      }
      for (int ni = 0; ni < 4; ++ni) {
        float bj = b[n0 + wn * 64 + ni * 16 + (lane & 15)];
        for (int mi = 0; mi < 4; ++mi) {
          int mg = m0 + wm * 64 + mi * 16 + ((lane >> 4) << 2);
          float* dst =
              xwxb + (size_t)mg * FH + n0 + wn * 64 + ni * 16 + (lane & 15);
          for (int r = 0; r < 4; ++r) dst[(size_t)r * FH] = acc[mi][ni][r] + bj;
        }
      }
    }
    gbar<2>(cntF, relF, ++genF, NWG);

    // -------- recurrent steps: 128 WGs, fence-free relaxed flag protocol ----
    if (wg < NSTEPWG) {
      const int rb = wg & 3, cg = wg >> 2;
      const int lc = wv * 16 + (lane & 15);
      const int gcl = wv * 512 + cg * 16 + (lane & 15);  // fallback Wh' row
      unsigned* myflag = &arrH[rb * 32 + cg];
      const unsigned* grpflags = &arrH[rb * 32];  // the 32 producers I depend on
      for (int tl = 0; tl < Tc; ++tl) {
        // top-of-step: all rb-group flags >= fl (relaxed sc1 polls, no inv)
        if (wv == 0) {
          int guard = 0;
          for (;;) {
            unsigned v = __hip_atomic_load(&grpflags[lane & 31],
                                           __ATOMIC_RELAXED,
                                           __HIP_MEMORY_SCOPE_AGENT);
            if (__all(v >= fl)) break;
            __builtin_amdgcn_s_sleep(1);
            if (++guard > (1 << 22)) break;
          }
        }
        __syncthreads();

        int tg = t0 + tl;
        const short* hc = (tg & 1) ? hbuf1 : hbuf0;
        short* hn = (tg & 1) ? hbuf0 : hbuf1;
        const short* arow =
            hc + (size_t)(rb * 16 + (lane & 15)) * K1 + (lane >> 4) * 8;
        f32x4 acc0 = {0.f, 0.f, 0.f, 0.f};
        f32x4 acc1 = {0.f, 0.f, 0.f, 0.f};
        bf16x8 ah[16];
#pragma unroll
        for (int k = 0; k < 16; ++k) ah[k] = ld16_cc(arow + k * 32);
        asm volatile("s_waitcnt vmcnt(0)" ::: "memory");
        __builtin_amdgcn_sched_barrier(0);
#pragma unroll
        for (int kk = 0; kk < 32; ++kk) {  // A-hi x (B-hi | B-lo)
          bf16x8 bv;
          if constexpr (LWH) {
            int k16 = 4 * kk + (lane >> 4);
            bv = *(const bf16x8*)(wlds + lc * K1 + ((k16 ^ (lc & 7)) << 3));
          } else {
            bv = *(const bf16x8*)(Wht + (size_t)gcl * K1 + kk * 32 +
                                  (lane >> 4) * 8);
          }
          if (kk & 1)
            acc1 = __builtin_amdgcn_mfma_f32_16x16x32_bf16(ah[kk & 15], bv,
                                                           acc1, 0, 0, 0);
          else
            acc0 = __builtin_amdgcn_mfma_f32_16x16x32_bf16(ah[kk & 15], bv,
                                                           acc0, 0, 0, 0);
        }
#pragma unroll
        for (int k = 0; k < 16; ++k) ah[k] = ld16_cc(arow + 512 + k * 32);
        asm volatile("s_waitcnt vmcnt(0)" ::: "memory");
        __builtin_amdgcn_sched_barrier(0);
#pragma unroll
        for (int kk = 0; kk < 16; ++kk) {  // A-lo x B-hi
          bf16x8 bv;
          if constexpr (LWH) {
            int k16 = 4 * kk + (lane >> 4);
            bv = *(const bf16x8*)(wlds + lc * K1 + ((k16 ^ (lc & 7)) << 3));
          } else {
            bv = *(const bf16x8*)(Wht + (size_t)gcl * K1 + kk * 32 +
                                  (lane >> 4) * 8);
          }
          if (kk & 1)
            acc1 = __builtin_amdgcn_mfma_f32_16x16x32_bf16(ah[kk], bv, acc1, 0,
                                                           0, 0);
          else
            acc0 = __builtin_amdgcn_mfma_f32_16x16x32_bf16(ah[kk], bv, acc0, 0,
                                                           0, 0);
        }
        f32x4 a = acc0 + acc1;
        for (int r = 0; r < 4; ++r)
          glds[wv][((lane >> 4) << 2) + r][lane & 15] = a[r];
        __syncthreads();
        {
          int row = tid >> 4, col = tid & 15;
          int n = rb * 16 + row, jh = cg * 16 + col;
          const float* xr = xwxb + ((size_t)tl * 64 + n) * FH + jh;
          float gi = glds[0][row][col] + xr[0];
          float gf = glds[1][row][col] + xr[512];
          float go = glds[2][row][col] + xr[1024];
          float gg = glds[3][row][col] + xr[1536];
          float si = 1.0f / (1.0f + __expf(-gi));
          float sf = 1.0f / (1.0f + __expf(-gf));
          float so = 1.0f / (1.0f + __expf(-go));
          float tg2 = tanhf(gg);
          float cn = sf * cbuf[n * H_ + jh] + si * tg2;
          cbuf[n * H_ + jh] = cn;
          float hv = so * tanhf(cn);
          out[((size_t)n * T_ + tg) * H_ + jh] = hv;
          unsigned short hi = f2bf(hv);
          unsigned short lo = f2bf(hv - bf2f(hi));
          unsigned ohi = (unsigned)__shfl_xor((int)(unsigned)hi, 1);
          unsigned olo = (unsigned)__shfl_xor((int)(unsigned)lo, 1);
          if (col & 1)
            st4_cc(hn + (size_t)n * K1 + 512 + (jh - 1),
                   olo | ((unsigned)lo << 16));
          else
            st4_cc(hn + (size_t)n * K1 + jh, (unsigned)hi | (ohi << 16));
        }
        asm volatile("s_waitcnt vmcnt(0)" ::: "memory");  // h in LLC
        __syncthreads();
        if (tid == 0)
          __hip_atomic_store(myflag, fl + 1, __ATOMIC_RELAXED,
                             __HIP_MEMORY_SCOPE_AGENT);
        ++fl;
      }
    } else {
      fl += Tc;
    }
    gbar<16>(cntF, relF, ++genF, NWG);
  }
}

extern "C" void kernel_launch(void* const* d_in, const int* in_sizes, int n_in,
                              void* d_out, int out_size, void* d_ws, size_t ws_size,
                              hipStream_t stream) {
  (void)in_sizes; (void)n_in; (void)out_size;
  const float* x  = (const float*)d_in[0];
  const float* h0 = (const float*)d_in[1];
  const float* Wx = (const float*)d_in[2];
  const float* Wh = (const float*)d_in[3];
  const float* b  = (const float*)d_in[4];
  float* out = (float*)d_out;

  size_t fixed = 1024 + 2 * (size_t)FH * K1 * 2 + 2 * (size_t)N_ * K1 * 2 +
                 (size_t)N_ * H_ * 4;
  size_t perTc = (size_t)N_ * K1 * 2 + (size_t)N_ * FH * 4;
  int Tc = 64;
  while (Tc > 1 && fixed + (size_t)Tc * perTc > ws_size) Tc >>= 1;

  (void)hipMemsetAsync(d_ws, 0, 1024, stream);  // reset barriers every replay

  void* args[] = {(void*)&x, (void*)&h0, (void*)&Wx, (void*)&Wh,
                  (void*)&b, (void*)&out, (void*)&d_ws, (void*)&Tc};

  // Path A: cooperative launch (static 148 KiB LDS -> 1 WG/CU, 256 WGs fit).
  hipError_t e = hipLaunchCooperativeKernel((void*)lstm_persistent<true>,
                                            dim3(NWG), dim3(BLK), args, 0,
                                            stream);
  if (e != hipSuccess) {
    // Path B: plain launch (custom barrier only needs co-residency).
    (void)hipGetLastError();
    lstm_persistent<true><<<dim3(NWG), dim3(BLK), 0, stream>>>(
        x, h0, Wx, Wh, b, out, d_ws, Tc);
    e = hipGetLastError();
  }
  if (e != hipSuccess) {
    // Path C: fallback — Wh read from global, tiny LDS.
    (void)hipGetLastError();
    lstm_persistent<false><<<dim3(NWG), dim3(BLK), 0, stream>>>(
        x, h0, Wx, Wh, b, out, d_ws, Tc);
    (void)hipGetLastError();
  }
}

// Round 7
// 2414.785 us; speedup vs baseline: 6.6923x; 1.7722x over previous
//
#include <hip/hip_runtime.h>
#include <hip/hip_bf16.h>

#define N_  64
#define T_  512
#define D_  512
#define H_  512
#define FH  2048   // 4H
#define K1  1024   // hi|lo packed columns
#define NWG 256
#define NSTEP 128
#define NHELP 128
#define BLK 256

typedef __attribute__((ext_vector_type(4))) float f32x4;
typedef __attribute__((ext_vector_type(8))) short bf16x8;

__device__ __forceinline__ unsigned short f2bf(float f) {
  unsigned u = __float_as_uint(f);
  return (unsigned short)((u + 0x7FFFu + ((u >> 16) & 1u)) >> 16);
}
__device__ __forceinline__ float bf2f(unsigned short s) {
  return __uint_as_float(((unsigned)s) << 16);
}
__device__ __forceinline__ float sigf(float x) {
  return 1.0f / (1.0f + __expf(-x));
}
__device__ __forceinline__ float tanhft(float x) {  // branch-free tanh
  x = fminf(15.f, fmaxf(-15.f, x));
  float e = __expf(2.f * x);
  return (e - 1.f) / (e + 1.f);
}

__device__ __forceinline__ void gl_lds16(const void* g, void* l) {
  __builtin_amdgcn_global_load_lds(
      (const __attribute__((address_space(1))) void*)g,
      (__attribute__((address_space(3))) void*)l, 16, 0, 0);
}

// LLC-coherent ops (sc0 sc1): proven cross-XCD handoff path (R5).
__device__ __forceinline__ bf16x8 ld16cc(const short* p) {
  bf16x8 d;
  asm volatile("global_load_dwordx4 %0, %1, off sc0 sc1" : "=v"(d) : "v"(p));
  return d;
}
__device__ __forceinline__ void st4cc(short* p, unsigned v) {
  asm volatile("global_store_dword %0, %1, off sc0 sc1" ::"v"(p), "v"(v)
               : "memory");
}
__device__ __forceinline__ unsigned ldflag(const unsigned* p) {
  unsigned v;
  asm volatile("global_load_dword %0, %1, off sc0 sc1\ns_waitcnt vmcnt(0)"
               : "=v"(v) : "v"(p) : "memory");
  return v;
}
__device__ __forceinline__ void stflag(unsigned* p, unsigned v) {
  asm volatile("global_store_dword %0, %1, off sc0 sc1" ::"v"(p), "v"(v)
               : "memory");
}

// Grid barrier over 256 WGs: parallel slot arrival + WG0 poller.
// One release/acquire fence pair per WG; relaxed (no per-poll inv) spins.
template <int SLP>
__device__ __forceinline__ void gbar2(unsigned* arr, unsigned* rel,
                                      unsigned gen, int wg) {
  __syncthreads();
  const int tid = threadIdx.x;
  if (tid == 0) {
    __builtin_amdgcn_fence(__ATOMIC_RELEASE, "agent");
    __hip_atomic_store(&arr[wg], gen, __ATOMIC_RELAXED,
                       __HIP_MEMORY_SCOPE_AGENT);
  }
  if (wg == 0) {
    if (tid < 64) {
      int guard = 0;
      for (;;) {
        unsigned v0 = __hip_atomic_load(&arr[tid], __ATOMIC_RELAXED,
                                        __HIP_MEMORY_SCOPE_AGENT);
        unsigned v1 = __hip_atomic_load(&arr[tid + 64], __ATOMIC_RELAXED,
                                        __HIP_MEMORY_SCOPE_AGENT);
        unsigned v2 = __hip_atomic_load(&arr[tid + 128], __ATOMIC_RELAXED,
                                        __HIP_MEMORY_SCOPE_AGENT);
        unsigned v3 = __hip_atomic_load(&arr[tid + 192], __ATOMIC_RELAXED,
                                        __HIP_MEMORY_SCOPE_AGENT);
        if (__all(v0 >= gen && v1 >= gen && v2 >= gen && v3 >= gen)) break;
        __builtin_amdgcn_s_sleep(SLP);
        if (++guard > (1 << 20)) break;
      }
    }
    __syncthreads();
    if (tid == 0)
      __hip_atomic_store(rel, gen, __ATOMIC_RELAXED, __HIP_MEMORY_SCOPE_AGENT);
  } else if (tid == 0) {
    int guard = 0;
    while (__hip_atomic_load(rel, __ATOMIC_RELAXED,
                             __HIP_MEMORY_SCOPE_AGENT) < gen) {
      __builtin_amdgcn_s_sleep(SLP);
      if (++guard > (1 << 20)) break;
    }
  }
  if (tid == 0) __builtin_amdgcn_fence(__ATOMIC_ACQUIRE, "agent");
  __syncthreads();
}

// Helper-group barrier (128 helper WGs), same scheme; poller hid==0.
template <int SLP>
__device__ __forceinline__ void hbar(unsigned* arr, unsigned* rel,
                                     unsigned gen, int hid) {
  __syncthreads();
  const int tid = threadIdx.x;
  if (tid == 0) {
    __builtin_amdgcn_fence(__ATOMIC_RELEASE, "agent");
    __hip_atomic_store(&arr[hid], gen, __ATOMIC_RELAXED,
                       __HIP_MEMORY_SCOPE_AGENT);
  }
  if (hid == 0) {
    if (tid < 64) {
      int guard = 0;
      for (;;) {
        unsigned v0 = __hip_atomic_load(&arr[tid], __ATOMIC_RELAXED,
                                        __HIP_MEMORY_SCOPE_AGENT);
        unsigned v1 = __hip_atomic_load(&arr[tid + 64], __ATOMIC_RELAXED,
                                        __HIP_MEMORY_SCOPE_AGENT);
        if (__all(v0 >= gen && v1 >= gen)) break;
        __builtin_amdgcn_s_sleep(SLP);
        if (++guard > (1 << 20)) break;
      }
    }
    __syncthreads();
    if (tid == 0)
      __hip_atomic_store(rel, gen, __ATOMIC_RELAXED, __HIP_MEMORY_SCOPE_AGENT);
  } else if (tid == 0) {
    int guard = 0;
    while (__hip_atomic_load(rel, __ATOMIC_RELAXED,
                             __HIP_MEMORY_SCOPE_AGENT) < gen) {
      __builtin_amdgcn_s_sleep(SLP);
      if (++guard > (1 << 20)) break;
    }
  }
  if (tid == 0) __builtin_amdgcn_fence(__ATOMIC_ACQUIRE, "agent");
  __syncthreads();
}

// x chunk -> hi/lo bf16 (octet-wise coalesced)
__device__ __forceinline__ void convert_x(const float* __restrict__ x,
                                          short* __restrict__ xprim, int t0,
                                          int Mch, int idx0, int stride) {
  for (int idx = idx0; idx < Mch * 64; idx += stride) {
    int mrow = idx >> 6, oct = idx & 63;
    int tl = mrow >> 6, n = mrow & 63;
    const float* src = x + ((size_t)n * T_ + (t0 + tl)) * D_ + oct * 8;
    bf16x8 hv, lv;
#pragma unroll
    for (int i = 0; i < 8; ++i) {
      float v = src[i];
      unsigned short h = f2bf(v);
      hv[i] = (short)h;
      lv[i] = (short)f2bf(v - bf2f(h));
    }
    *(bf16x8*)(xprim + (size_t)mrow * K1 + oct * 8) = hv;
    *(bf16x8*)(xprim + (size_t)mrow * K1 + 512 + oct * 8) = lv;
  }
}

// Phase-1 GEMM: xw = x' @ Wx' + b (128x128 tiles, K'=1536, split-bf16)
__device__ __forceinline__ void phase1(const short* __restrict__ xprim,
                                       const short* __restrict__ Wxt,
                                       const float* __restrict__ b,
                                       float* __restrict__ xw, int nTiles,
                                       int tile0, int tstride, short* Asm,
                                       short* Bsm) {
  const int tid = threadIdx.x;
  const int lane = tid & 63, wv = tid >> 6;
  const int wm = wv >> 1, wn = wv & 1;
  const int sslot = (lane & 3) ^ ((lane >> 3) & 3);
  for (int tile = tile0; tile < nTiles; tile += tstride) {
    int tm = tile >> 4, tn = tile & 15;
    int m0 = tm << 7, n0 = tn << 7;
    f32x4 acc[4][4];
    for (int i = 0; i < 4; ++i)
      for (int j = 0; j < 4; ++j) acc[i][j] = (f32x4){0.f, 0.f, 0.f, 0.f};
    for (int kk = 0; kk < 48; ++kk) {
      int ac = (kk < 16 ? kk : kk - 16) << 5;
      int bc = (kk < 32 ? kk : kk - 32) << 5;
      __syncthreads();
      {
        const short* sa =
            xprim + (size_t)(m0 + wv * 32 + (lane >> 2)) * K1 + ac + sslot * 8;
        gl_lds16(sa, Asm + (wv * 32) * 32);
        gl_lds16(sa + (size_t)16 * K1, Asm + (wv * 32 + 16) * 32);
        const short* sb =
            Wxt + (size_t)(n0 + wv * 32 + (lane >> 2)) * K1 + bc + sslot * 8;
        gl_lds16(sb, Bsm + (wv * 32) * 32);
        gl_lds16(sb + (size_t)16 * K1, Bsm + (wv * 32 + 16) * 32);
      }
      __syncthreads();
      bf16x8 af[4], bfr[4];
      for (int mi = 0; mi < 4; ++mi) {
        int R = wm * 64 + mi * 16 + (lane & 15);
        int rs = ((lane >> 4) & 3) ^ ((R >> 1) & 3);
        af[mi] = *(const bf16x8*)(Asm + R * 32 + rs * 8);
      }
      for (int ni = 0; ni < 4; ++ni) {
        int R = wn * 64 + ni * 16 + (lane & 15);
        int rs = ((lane >> 4) & 3) ^ ((R >> 1) & 3);
        bfr[ni] = *(const bf16x8*)(Bsm + R * 32 + rs * 8);
      }
      for (int mi = 0; mi < 4; ++mi)
        for (int ni = 0; ni < 4; ++ni)
          acc[mi][ni] = __builtin_amdgcn_mfma_f32_16x16x32_bf16(
              af[mi], bfr[ni], acc[mi][ni], 0, 0, 0);
    }
    for (int ni = 0; ni < 4; ++ni) {
      float bj = b[n0 + wn * 64 + ni * 16 + (lane & 15)];
      for (int mi = 0; mi < 4; ++mi) {
        int mg = m0 + wm * 64 + mi * 16 + ((lane >> 4) << 2);
        float* dst = xw + (size_t)mg * FH + n0 + wn * 64 + ni * 16 + (lane & 15);
        for (int r = 0; r < 4; ++r) dst[(size_t)r * FH] = acc[mi][ni][r] + bj;
      }
    }
  }
}

// Recurrent steps (LLC sc0sc1 handoff; h staged via 16KB LDS, hi then lo).
template <bool LWH>
__device__ __forceinline__ void run_steps(
    int rb, int cg, int t0, int Tc, unsigned& fl, const short* wlds,
    const short* __restrict__ Wht, short* hbuf0, short* hbuf1, float* cbuf,
    const float* __restrict__ xw, float* __restrict__ out, unsigned* arrH,
    short* hst, float (*glds)[16][16]) {
  const int tid = threadIdx.x;
  const int lane = tid & 63, wv = tid >> 6;
  const int lc = wv * 16 + (lane & 15);
  const int gcl = wv * 512 + cg * 16 + (lane & 15);
  const int row = tid >> 4, col = tid & 15;
  const int n = rb * 16 + row, jh = cg * 16 + col;
  unsigned* myflag = &arrH[rb * 64 + cg];
  unsigned* grp = &arrH[rb * 64];
  for (int tl = 0; tl < Tc; ++tl) {
    const int tg = t0 + tl;
    // gate inputs + c (independent of h): load before the poll
    const float* xr = xw + ((size_t)tl * 64 + n) * FH + jh;
    float x0 = xr[0], x1 = xr[512], x2 = xr[1024], x3 = xr[1536];
    float cprev = cbuf[n * H_ + jh];
    if (wv == 0) {
      int guard = 0;
      for (;;) {
        unsigned v = ldflag(grp + (lane & 31));
        if (__all(v >= fl)) break;
        __builtin_amdgcn_s_sleep(1);
        if (++guard > (1 << 20)) break;
      }
    }
    __syncthreads();
    const short* hc = (tg & 1) ? hbuf1 : hbuf0;
    short* hn = (tg & 1) ? hbuf0 : hbuf1;

    // ---- stage hi-half (16 rows x 512 shorts) into LDS, XOR-swizzled ----
    {
      bf16x8 tmp[4];
#pragma unroll
      for (int i = 0; i < 4; ++i) {
        int idx = tid * 4 + i, r = idx >> 6, c = idx & 63;
        tmp[i] = ld16cc(hc + (size_t)(rb * 16 + r) * K1 + c * 8);
      }
      asm volatile("s_waitcnt vmcnt(0)" ::: "memory");
      __builtin_amdgcn_sched_barrier(0);
#pragma unroll
      for (int i = 0; i < 4; ++i) {
        int idx = tid * 4 + i, r = idx >> 6, c = idx & 63;
        *(bf16x8*)(hst + r * 512 + ((c ^ (r & 7)) << 3)) = tmp[i];
      }
    }
    __syncthreads();
    // hi fragments -> regs (each wave reads the shared A rows from LDS)
    bf16x8 af[16];
#pragma unroll
    for (int kk = 0; kk < 16; ++kk) {
      int c = kk * 4 + (lane >> 4), r = lane & 15;
      af[kk] = *(const bf16x8*)(hst + r * 512 + ((c ^ (r & 7)) << 3));
    }
    __syncthreads();  // all hst reads done -> buffer free for lo

    // issue lo-half global loads; their latency hides under the hi MFMAs
    bf16x8 tlo[4];
#pragma unroll
    for (int i = 0; i < 4; ++i) {
      int idx = tid * 4 + i, r = idx >> 6, c = idx & 63;
      tlo[i] = ld16cc(hc + (size_t)(rb * 16 + r) * K1 + 512 + c * 8);
    }
    f32x4 acc0 = {0.f, 0.f, 0.f, 0.f};
    f32x4 acc1 = {0.f, 0.f, 0.f, 0.f};
#pragma unroll
    for (int kk = 0; kk < 32; ++kk) {  // A-hi x (B-hi | B-lo)
      bf16x8 bv;
      if constexpr (LWH) {
        int k16 = 4 * kk + (lane >> 4);
        bv = *(const bf16x8*)(wlds + lc * K1 + ((k16 ^ (lc & 7)) << 3));
      } else {
        bv = *(const bf16x8*)(Wht + (size_t)gcl * K1 + kk * 32 + (lane >> 4) * 8);
      }
      if (kk & 1)
        acc1 = __builtin_amdgcn_mfma_f32_16x16x32_bf16(af[kk & 15], bv, acc1,
                                                       0, 0, 0);
      else
        acc0 = __builtin_amdgcn_mfma_f32_16x16x32_bf16(af[kk & 15], bv, acc0,
                                                       0, 0, 0);
    }
    asm volatile("s_waitcnt vmcnt(0)" ::: "memory");
    __builtin_amdgcn_sched_barrier(0);
#pragma unroll
    for (int i = 0; i < 4; ++i) {
      int idx = tid * 4 + i, r = idx >> 6, c = idx & 63;
      *(bf16x8*)(hst + r * 512 + ((c ^ (r & 7)) << 3)) = tlo[i];
    }
    __syncthreads();
#pragma unroll
    for (int kk = 0; kk < 16; ++kk) {  // A-lo x B-hi
      int c = kk * 4 + (lane >> 4), r = lane & 15;
      bf16x8 al = *(const bf16x8*)(hst + r * 512 + ((c ^ (r & 7)) << 3));
      bf16x8 bv;
      if constexpr (LWH) {
        int k16 = 4 * kk + (lane >> 4);
        bv = *(const bf16x8*)(wlds + lc * K1 + ((k16 ^ (lc & 7)) << 3));
      } else {
        bv = *(const bf16x8*)(Wht + (size_t)gcl * K1 + kk * 32 + (lane >> 4) * 8);
      }
      if (kk & 1)
        acc1 = __builtin_amdgcn_mfma_f32_16x16x32_bf16(al, bv, acc1, 0, 0, 0);
      else
        acc0 = __builtin_amdgcn_mfma_f32_16x16x32_bf16(al, bv, acc0, 0, 0, 0);
    }
    f32x4 a = acc0 + acc1;
    for (int r = 0; r < 4; ++r)
      glds[wv][((lane >> 4) << 2) + r][lane & 15] = a[r];
    __syncthreads();
    {
      float gi = glds[0][row][col] + x0;
      float gf = glds[1][row][col] + x1;
      float go = glds[2][row][col] + x2;
      float gg = glds[3][row][col] + x3;
      float si = sigf(gi), sf = sigf(gf), so = sigf(go);
      float tg2 = tanhft(gg);
      float cn = sf * cprev + si * tg2;
      float hv = so * tanhft(cn);
      unsigned short hi2 = f2bf(hv);
      unsigned short lo2 = f2bf(hv - bf2f(hi2));
      unsigned ohi = (unsigned)__shfl_xor((int)(unsigned)hi2, 1);
      unsigned olo = (unsigned)__shfl_xor((int)(unsigned)lo2, 1);
      if (col & 1)
        st4cc(hn + (size_t)n * K1 + 512 + (jh - 1), olo | ((unsigned)lo2 << 16));
      else
        st4cc(hn + (size_t)n * K1 + jh, (unsigned)hi2 | (ohi << 16));
      // h committed to LLC, THEN publish; out/cbuf off the critical path
      asm volatile("s_waitcnt vmcnt(0)" ::: "memory");
      __syncthreads();
      if (tid == 0) stflag(myflag, fl + 1);
      cbuf[n * H_ + jh] = cn;
      out[((size_t)n * T_ + tg) * H_ + jh] = hv;
    }
    ++fl;
  }
}

template <bool LWH>
__global__ void __launch_bounds__(BLK, 1)
lstm_persistent(const float* __restrict__ x, const float* __restrict__ h0,
                const float* __restrict__ Wx, const float* __restrict__ Wh,
                const float* __restrict__ b, float* __restrict__ out,
                void* __restrict__ ws, int Tc) {
  __shared__ __align__(16) short wlds[LWH ? 64 * K1 : 8];  // 128 KiB Wh slice
  __shared__ __align__(16) short sbuf[8192];  // 16 KiB: phase1 A/B | h stage
  __shared__ float glds[4][16][16];           // 4 KiB gate exchange

  char* wsb = (char*)ws;
  unsigned* relF = (unsigned*)(wsb + 0);
  unsigned* arrF = (unsigned*)(wsb + 256);    // [256]
  unsigned* relJ = (unsigned*)(wsb + 1280);
  unsigned* arrJ = (unsigned*)(wsb + 1344);   // [128]
  unsigned* arrH = (unsigned*)(wsb + 2048);   // [4][64] step flags
  short* Wxt   = (short*)(wsb + 4096);        // [2048][1024] bf16 hi|lo, W^T
  short* Wht   = Wxt + (size_t)FH * K1;
  short* hbuf0 = Wht + (size_t)FH * K1;       // [64][1024]
  short* hbuf1 = hbuf0 + N_ * K1;
  float* cbuf  = (float*)(hbuf1 + N_ * K1);   // [64][512] f32
  short* xprim = (short*)(cbuf + N_ * H_);    // [Tc*64][1024]
  float* xwxb  = (float*)(xprim + (size_t)Tc * N_ * K1);  // 2 x [Tc*64][2048]

  const int tid = threadIdx.x;
  const int wg = blockIdx.x;
  const int gtid = wg * BLK + tid;
  const bool isStep = wg < NSTEP;
  const int rb = wg >> 5, cg = wg & 31;  // steppers
  const int hid = wg - NSTEP;            // helpers

  unsigned genF = 0, genJ = 0, fl = 0;

  // ---- prep: split-transpose weights (octet-wise), h0, c0 ----
  for (int idx = gtid; idx < 2 * FH * 64; idx += NWG * BLK) {
    int m = idx >> 17;
    int rr = idx & 131071;
    int j = rr >> 6;
    int oct = rr & 63;
    const float* W = m ? Wh : Wx;
    bf16x8 hv, lv;
#pragma unroll
    for (int i = 0; i < 8; ++i) {
      float v = W[(size_t)(oct * 8 + i) * FH + j];
      unsigned short h = f2bf(v);
      hv[i] = (short)h;
      lv[i] = (short)f2bf(v - bf2f(h));
    }
    short* dst = m ? Wht : Wxt;
    *(bf16x8*)(dst + (size_t)j * K1 + oct * 8) = hv;
    *(bf16x8*)(dst + (size_t)j * K1 + 512 + oct * 8) = lv;
  }
  for (int idx = gtid; idx < N_ * H_; idx += NWG * BLK) {
    int n = idx >> 9, k = idx & 511;
    float v = h0[idx];
    unsigned short hi = f2bf(v);
    unsigned short lo = f2bf(v - bf2f(hi));
    hbuf0[n * K1 + k] = (short)hi;
    hbuf0[n * K1 + 512 + k] = (short)lo;
    cbuf[idx] = 0.0f;
  }
  gbar2<4>(arrF, relF, ++genF, wg);

  // ---- steppers: Wh slice -> LDS (XOR-swizzled 16B units) ----
  if constexpr (LWH) {
    if (isStep) {
      for (int u = tid; u < 64 * 128; u += BLK) {
        int lc = u >> 7, k16 = u & 127;
        int gc = ((lc >> 4) << 9) + cg * 16 + (lc & 15);
        int4 v = *(const int4*)(Wht + (size_t)gc * K1 + k16 * 8);
        *(int4*)(wlds + lc * K1 + ((k16 ^ (lc & 7)) << 3)) = v;
      }
    }
    __syncthreads();
  }

  const int nCh = T_ / Tc;
  const int Mch = Tc * N_;
  const int nTiles = (Mch >> 7) * (FH >> 7);
  const size_t xwStride = (size_t)Mch * FH;

  // ---- chunk 0 front work (all WGs) ----
  convert_x(x, xprim, 0, Mch, gtid, NWG * BLK);
  gbar2<2>(arrF, relF, ++genF, wg);
  phase1(xprim, Wxt, b, xwxb, nTiles, wg, NWG, sbuf, sbuf + 4096);
  gbar2<2>(arrF, relF, ++genF, wg);

  // ---- pipelined chunks: steps(ch) on WGs 0-127 || GEMM(ch+1) on 128-255 ----
  for (int ch = 0; ch < nCh; ++ch) {
    const int t0 = ch * Tc;
    if (isStep) {
      const float* xw = xwxb + (size_t)(ch & 1) * xwStride;
      run_steps<LWH>(rb, cg, t0, Tc, fl, wlds, Wht, hbuf0, hbuf1, cbuf, xw,
                     out, arrH, sbuf, glds);
    } else if (ch + 1 < nCh) {
      convert_x(x, xprim, t0 + Tc, Mch, hid * BLK + tid, NHELP * BLK);
      hbar<1>(arrJ, relJ, ++genJ, hid);
      phase1(xprim, Wxt, b, xwxb + (size_t)((ch + 1) & 1) * xwStride, nTiles,
             hid, NHELP, sbuf, sbuf + 4096);
    }
    gbar2<8>(arrF, relF, ++genF, wg);
  }
}

extern "C" void kernel_launch(void* const* d_in, const int* in_sizes, int n_in,
                              void* d_out, int out_size, void* d_ws, size_t ws_size,
                              hipStream_t stream) {
  (void)in_sizes; (void)n_in; (void)out_size;
  const float* x  = (const float*)d_in[0];
  const float* h0 = (const float*)d_in[1];
  const float* Wx = (const float*)d_in[2];
  const float* Wh = (const float*)d_in[3];
  const float* b  = (const float*)d_in[4];
  float* out = (float*)d_out;

  // ws: 4KB barriers + 8MB weights + h/c + Tc*(x' 128KB + 2x xwxb 512KB)
  size_t fixed = 4096 + 2 * (size_t)FH * K1 * 2 + 2 * (size_t)N_ * K1 * 2 +
                 (size_t)N_ * H_ * 4;
  size_t perTc = (size_t)N_ * K1 * 2 + 2 * (size_t)N_ * FH * 4;
  int Tc = 64;
  while (Tc > 1 && fixed + (size_t)Tc * perTc > ws_size) Tc >>= 1;

  (void)hipMemsetAsync(d_ws, 0, 4096, stream);  // reset barriers every replay

  void* args[] = {(void*)&x, (void*)&h0, (void*)&Wx, (void*)&Wh,
                  (void*)&b, (void*)&out, (void*)&d_ws, (void*)&Tc};

  // Path A: cooperative launch (static 148 KiB LDS -> 1 WG/CU, 256 WGs fit).
  hipError_t e = hipLaunchCooperativeKernel((void*)lstm_persistent<true>,
                                            dim3(NWG), dim3(BLK), args, 0,
                                            stream);
  if (e != hipSuccess) {
    // Path B: plain launch (custom barriers only need co-residency).
    (void)hipGetLastError();
    lstm_persistent<true><<<dim3(NWG), dim3(BLK), 0, stream>>>(
        x, h0, Wx, Wh, b, out, d_ws, Tc);
    e = hipGetLastError();
  }
  if (e != hipSuccess) {
    // Path C: fallback — Wh read from global, tiny LDS.
    (void)hipGetLastError();
    lstm_persistent<false><<<dim3(NWG), dim3(BLK), 0, stream>>>(
        x, h0, Wx, Wh, b, out, d_ws, Tc);
    (void)hipGetLastError();
  }
}